// Round 10
// baseline (179.143 us; speedup 1.0000x reference)
//
#include <hip/hip_runtime.h>
#include <math.h>

// MMD loss, fp16 MFMA. N=M=4096, D=1024, sigma^2=2025.
// Round 20: B DIRECT-TO-REG inside the R7 TLP structure. R9 (BK=64) fired
// its falsifier (92us): barrier pairs aren't the tax. R7 = 84.8us = 823 TF
// effective -- AT the documented ~874-912 TF ceiling of the 128^2/2-barrier
// structure. Budget: MFMA 35%, LDS ~48% (48KB/step), rest latency/barrier.
// The co-pole is LDS service. R5's B-to-regs failed at 1 block/CU (naked
// vmcnt gate); here the SAME transform runs under 3-blocks/CU TLP with
// plain compiler-scheduled loads: B frags read straight from the packed
// panel (per frag: contiguous 1KB/wave, 16B/lane), issued at the top of
// the compute region where ds_reads + sibling blocks hide them. LDS halves
// to A-only (24KB/step); staging instrs 16->8 (shorter drain); B served by
// L1/L2 (waves 0/2 & 1/3 read identical addresses -> broadcast). Regs:
// ~90 arch + 64 acc ~= 154 -> 3 waves/SIMD preserved.
// Unchanged from R7: packed K-major [kt][row][32] panels (1KB-contiguous
// glds), A chunk-swizzle f(r)=((r>>1)&3) (measured 0 conflicts), 2-barrier
// drain loop, triangular 2080-block grid, fp64 partials, 3 launches.

typedef _Float16 f16_t;
typedef _Float16 f16x4 __attribute__((ext_vector_type(4)));
typedef _Float16 f16x8 __attribute__((ext_vector_type(8)));
typedef float floatx4 __attribute__((ext_vector_type(4)));

#define NROWS 4096
#define MROWS 4096
#define DDIM  1024
#define BM    128
#define BK    32                      // fp16 elements per K-step (64 B/row)
#define TILE  (BM * BK)               // 4096 f16 per tile (8 KB)
#define NKT   (DDIM / BK)             // 32 K-steps
#define PSTRIDE (4096 * BK)           // f16 elems per packed K-panel (256 KB)
#define NT    (NROWS / BM)            // 32 tiles per dim
#define TRI   (NT * (NT + 1) / 2)     // 528 triangular tiles
#define NBLK  (2 * TRI + NT * NT)     // 2080 blocks

// ---------------------------------------------------------------- convert
// Wave-per-row: 2048 blocks x 4 waves cover 8192 rows. Each lane loads
// 4 float4 (fully coalesced), converts to fp16, stores to the PACKED layout
// Xp[kt][row][32]: lane l, iter c covers k = c*256+l*4 -> panel c*8+(l>>3),
// pos (l&7)*4. Norm of the ROUNDED row shuffle-reduced in-wave.
__global__ __launch_bounds__(256) void convert_kernel(
    const float* __restrict__ X, const float* __restrict__ Y,
    f16_t* __restrict__ Xp, f16_t* __restrict__ Yp,
    float* __restrict__ nx, float* __restrict__ ny) {
    const int wid  = threadIdx.x >> 6;
    const int lane = threadIdx.x & 63;
    const int row  = blockIdx.x * 4 + wid;        // 0..8191
    const float* src;
    f16_t* dstp;
    float* nrm;
    int r;
    if (row < NROWS) {
        r = row;         src = X + (size_t)r * DDIM;
        dstp = Xp;  nrm = nx;
    } else {
        r = row - NROWS; src = Y + (size_t)r * DDIM;
        dstp = Yp;  nrm = ny;
    }
    const float4* s4 = (const float4*)src;        // 256 float4 per row
    float s = 0.f;
    #pragma unroll
    for (int c = 0; c < 4; c++) {
        float4 v = s4[c * 64 + lane];
        f16x4 h;
        h[0] = (f16_t)v.x; h[1] = (f16_t)v.y;
        h[2] = (f16_t)v.z; h[3] = (f16_t)v.w;
        // k = c*256 + lane*4 -> kt = c*8 + (lane>>3), pos = (lane&7)*4
        *(f16x4*)(dstp + (size_t)(c * 8 + (lane >> 3)) * PSTRIDE
                       + (size_t)r * BK + (lane & 7) * 4) = h;
        float h0 = (float)h[0], h1 = (float)h[1];
        float h2 = (float)h[2], h3 = (float)h[3];
        s += h0 * h0 + h1 * h1 + h2 * h2 + h3 * h3;
    }
    #pragma unroll
    for (int off = 32; off > 0; off >>= 1) s += __shfl_down(s, off);
    if (lane == 0) nrm[r] = s;
}

// ---------------------------------------------------------------- main GEMM
__global__ __launch_bounds__(256) void mmd_mfma(
    const f16_t* __restrict__ Xp, const f16_t* __restrict__ Yp,
    const float* __restrict__ nx, const float* __restrict__ ny,
    double* __restrict__ partials) {
    // A-only LDS tile: 128x32 fp16 = 8 KB. Row r stores logical chunk c
    // (16B) at phys chunk c ^ ((r>>1)&3) -- measured 0 bank conflicts (R7).
    __shared__ __align__(16) f16_t ldsA[TILE];
    __shared__ double wred[4];

    const int b = blockIdx.x;
    const f16_t *Ap, *Bp;             // packed panel bases (panel 0)
    const float *nA, *nB;
    int tr, tc;
    double coef;
    if (b < 2 * TRI) {
        int u = (b < TRI) ? b : b - TRI;
        int r = 0;
        while (u >= NT - r) { u -= NT - r; r++; }
        tr = r; tc = r + u;
        double w = (tr == tc) ? 1.0 : 2.0;   // off-diagonal tiles count twice
        if (b < TRI) { Ap = Xp; Bp = Xp; nA = nx; nB = nx;
                       coef = w / ((double)NROWS * (double)(NROWS - 1)); }
        else         { Ap = Yp; Bp = Yp; nA = ny; nB = ny;
                       coef = w / ((double)MROWS * (double)(MROWS - 1)); }
    } else {
        int u = b - 2 * TRI;
        tr = u >> 5; tc = u & 31;
        Ap = Xp; Bp = Yp; nA = nx; nB = ny;
        coef = -2.0 / ((double)NROWS * (double)MROWS);
    }

    const int t    = threadIdx.x;
    const int wave = t >> 6;            // 0..3; waves 2x2: wm=wave>>1, wn=wave&1
    const int lane = t & 63;
    const int wm   = wave >> 1;
    const int wn   = wave & 1;

    // A staging: 8 glds instrs (8 row-groups of 16 rows); wave w issues
    // instrs w*2 .. w*2+1. Per instr: 16 rows x 64B = CONTIGUOUS 1KB in the
    // packed panel. glds writes linearly: lane l -> row lr=l>>2, phys chunk
    // l&3; lane fetches global chunk (l&3)^((l>>3)&3) so phys chunk p of
    // row r holds logical p^((r>>1)&3).
    const int lr = lane >> 2;           // 0..15 within row-group
    const int lc = (lane & 3) ^ ((lane >> 3) & 3);
    const f16_t* gsrc[2];
    f16_t* ldst[2];
    #pragma unroll
    for (int i = 0; i < 2; i++) {
        int rg = wave * 2 + i;          // 0..7
        gsrc[i] = Ap + (size_t)(tr * BM + rg * 16 + lr) * BK + lc * 8;
        ldst[i] = ldsA + rg * 16 * BK;  // wave-uniform base
    }

    const int m    = lane & 15;         // row within 16x16 subtile
    const int quad = lane >> 4;         // k-chunk: k = quad*8 + j
    // A read-side swizzled chunk offset: phys = quad ^ ((row>>1)&3); rows
    // are s*16 + m so f depends only on m.
    const int sw8  = (quad ^ ((m >> 1) & 3)) * 8;

    // B fragment pointer (direct-from-global, logical order, no swizzle):
    // row (tc*BM + wn*64 + s*16 + m), 16B chunk quad. Per frag s the wave
    // covers 16 rows x 64B = contiguous 1KB (16B/lane).
    const f16_t* gB = Bp + (size_t)(tc * BM + wn * 64 + m) * BK + quad * 8;

    // hoist epilogue norm loads off the critical tail
    float na[16], nb[4];
    #pragma unroll
    for (int i = 0; i < 4; i++) {
        #pragma unroll
        for (int r = 0; r < 4; r++)
            na[i * 4 + r] = nA[tr * BM + wm * 64 + i * 16 + quad * 4 + r];
        nb[i] = nB[tc * BM + wn * 64 + i * 16 + m];
    }

    floatx4 acc_r[4][4];
    #pragma unroll
    for (int i = 0; i < 4; i++)
        #pragma unroll
        for (int j = 0; j < 4; j++) acc_r[i][j] = (floatx4){0.f, 0.f, 0.f, 0.f};

    for (int kt = 0; kt < NKT; kt++) {
        const size_t ko = (size_t)kt * PSTRIDE;   // next packed K-panel
        __syncthreads();                 // previous compute done before overwrite
        #pragma unroll
        for (int i = 0; i < 2; i++) {
            __builtin_amdgcn_global_load_lds(
                (const __attribute__((address_space(1))) void*)(gsrc[i] + ko),
                (__attribute__((address_space(3))) void*)ldst[i],
                16, 0, 0);
        }
        __syncthreads();                 // drains vmcnt before barrier

        // B global loads first (long latency; hidden by ds_reads + TLP)
        f16x8 bh[4];
        #pragma unroll
        for (int s = 0; s < 4; s++)
            bh[s] = *(const f16x8*)(gB + ko + s * 16 * BK);
        f16x8 ah[4];
        #pragma unroll
        for (int s = 0; s < 4; s++)
            ah[s] = *(const f16x8*)&ldsA[(wm * 64 + s * 16 + m) * BK + sw8];
        #pragma unroll
        for (int i = 0; i < 4; i++)
            #pragma unroll
            for (int j = 0; j < 4; j++)
                acc_r[i][j] = __builtin_amdgcn_mfma_f32_16x16x32_f16(ah[i], bh[j], acc_r[i][j], 0, 0, 0);
    }

    // epilogue: C/D layout col=lane&15 (B-row), row=quad*4+reg (A-row)
    const float inv_s2 = 1.0f / 2025.0f;
    float lsum = 0.f;
    #pragma unroll
    for (int i = 0; i < 4; i++)
        #pragma unroll
        for (int j = 0; j < 4; j++)
            #pragma unroll
            for (int r = 0; r < 4; r++) {
                float arg = (2.f * acc_r[i][j][r] - na[i * 4 + r] - nb[j]) * inv_s2;
                lsum += __expf(arg);
            }

    // in-wave fp64 reduce (no barriers), then 4-wave LDS combine; plain store
    double d = (double)lsum;
    #pragma unroll
    for (int off = 32; off > 0; off >>= 1) d += __shfl_down(d, off);
    if (lane == 0) wred[wave] = d;
    __syncthreads();
    if (t == 0)
        partials[b] = (wred[0] + wred[1] + wred[2] + wred[3]) * coef;
}

__global__ __launch_bounds__(256) void final_reduce(const double* __restrict__ partials,
                                                    float* __restrict__ out) {
    __shared__ double red[256];
    int t = threadIdx.x;
    double s = 0.0;
    for (int i = t; i < NBLK; i += 256) s += partials[i];
    red[t] = s;
    __syncthreads();
    for (int off = 128; off > 0; off >>= 1) {
        if (t < off) red[t] += red[t + off];
        __syncthreads();
    }
    if (t == 0) {
        // analytic diagonal subtraction: 1/(n-1) + 1/(m-1)
        double mmd = red[0] - 1.0 / (double)(NROWS - 1) - 1.0 / (double)(MROWS - 1);
        out[0] = (float)mmd;
    }
}

extern "C" void kernel_launch(void* const* d_in, const int* in_sizes, int n_in,
                              void* d_out, int out_size, void* d_ws, size_t ws_size,
                              hipStream_t stream) {
    const float* X = (const float*)d_in[0];   // inputs  [4096,1024] fp32
    const float* Y = (const float*)d_in[1];   // samples [4096,1024] fp32
    float* out = (float*)d_out;

    // workspace: partials | nx | ny | Xp | Yp  (~16.7 MB)
    char* p = (char*)d_ws;
    double* partials = (double*)p;            p += ((size_t)NBLK * sizeof(double) + 255) & ~255ULL;
    float* nx = (float*)p;                    p += (size_t)NROWS * sizeof(float);
    float* ny = (float*)p;                    p += (size_t)MROWS * sizeof(float);
    f16_t* Xp = (f16_t*)p;                    p += (size_t)NROWS * DDIM * sizeof(f16_t);
    f16_t* Yp = (f16_t*)p;

    convert_kernel<<<(NROWS + MROWS) / 4, 256, 0, stream>>>(X, Y, Xp, Yp, nx, ny);
    mmd_mfma<<<NBLK, 256, 0, stream>>>(Xp, Yp, nx, ny, partials);
    final_reduce<<<1, 256, 0, stream>>>(partials, out);
}

// Round 11
// 158.825 us; speedup vs baseline: 1.1279x; 1.1279x over previous
//
#include <hip/hip_runtime.h>
#include <math.h>

// MMD loss, fp16 MFMA. N=M=4096, D=1024, sigma^2=2025.
// Round 21: FIX THE CONVERT KERNEL (the overlooked constant). Across all 11
// rounds, total - mmd ~= 70us CONSTANT: convert ~55-60us (5x its ~12us
// roofline; its packed-layout stores were 8B/lane scattered into 8 panels
// 256KB apart -> partial-line writes + page thrash at ~0.9 TB/s), reduce
// ~4us, launch ~6us. New convert: LDS-staged transpose. Block owns 8 rows:
// phase 1 loads fp32 coalesced (float4/lane), converts, stages sh[8][1024]
// f16 (16KB), norms shuffle-reduced; phase 2 writes panel-major -- per
// iteration each wave stores ONE panel's 8-row segment as a fully
// contiguous 512B (64 lanes x f16x4), 8 iters covering 32 panels. Every
// store covers whole lines; no RMW. 1024 blocks x 4 waves.
// mmd_mfma + final_reduce: R7 VERBATIM (best measured: 84.8us, MfmaUtil
// 35%, conflicts 0; every structural deviation since regressed). R10's
// B-to-regs falsifier fired -> staged-LDS operands are strictly better in
// the TLP structure; structure is at its ~823TF equilibrium.

typedef _Float16 f16_t;
typedef _Float16 f16x4 __attribute__((ext_vector_type(4)));
typedef _Float16 f16x8 __attribute__((ext_vector_type(8)));
typedef float floatx4 __attribute__((ext_vector_type(4)));

#define NROWS 4096
#define MROWS 4096
#define DDIM  1024
#define BM    128
#define BK    32                      // fp16 elements per K-step (64 B/row)
#define TILE  (BM * BK)               // 4096 f16 per tile (8 KB)
#define NKT   (DDIM / BK)             // 32 K-steps
#define PSTRIDE (4096 * BK)           // f16 elems per packed K-panel (256 KB)
#define NT    (NROWS / BM)            // 32 tiles per dim
#define TRI   (NT * (NT + 1) / 2)     // 528 triangular tiles
#define NBLK  (2 * TRI + NT * NT)     // 2080 blocks

// ---------------------------------------------------------------- convert
// 1024 blocks x 256 threads; block owns 8 rows (blocks 0..511 -> X,
// 512..1023 -> Y). Phase 1: wave w converts rows w*2, w*2+1 (float4/lane
// coalesced loads), stages fp16 in sh[8][1024], norm of the ROUNDED row
// shuffle-reduced in-wave. Phase 2: per iter g, wave w writes panel
// g*4+w's 8-row segment: 64 lanes x f16x4 = 512B FULLY CONTIGUOUS at
// Xp[p][r0..r0+7][0..31] (rows are 64B apart and adjacent in the panel).
__global__ __launch_bounds__(256) void convert_kernel(
    const float* __restrict__ X, const float* __restrict__ Y,
    f16_t* __restrict__ Xp, f16_t* __restrict__ Yp,
    float* __restrict__ nx, float* __restrict__ ny) {
    __shared__ __align__(16) f16_t sh[8][DDIM];   // 16 KB

    const int wave = threadIdx.x >> 6;
    const int lane = threadIdx.x & 63;
    const int bb   = blockIdx.x;
    const float* src;
    f16_t* dstp;
    float* nrm;
    int r0;
    if (bb < 512) { r0 = bb * 8;         src = X + (size_t)r0 * DDIM;
                    dstp = Xp;  nrm = nx; }
    else          { r0 = (bb - 512) * 8; src = Y + (size_t)r0 * DDIM;
                    dstp = Yp;  nrm = ny; }

    // phase 1: convert + stage + norms
    #pragma unroll
    for (int rr = 0; rr < 2; rr++) {
        const int lr = wave * 2 + rr;               // 0..7
        const float4* s4 = (const float4*)(src + (size_t)lr * DDIM);
        float s = 0.f;
        #pragma unroll
        for (int c = 0; c < 4; c++) {
            float4 v = s4[c * 64 + lane];
            f16x4 h;
            h[0] = (f16_t)v.x; h[1] = (f16_t)v.y;
            h[2] = (f16_t)v.z; h[3] = (f16_t)v.w;
            *(f16x4*)&sh[lr][c * 256 + lane * 4] = h;
            float h0 = (float)h[0], h1 = (float)h[1];
            float h2 = (float)h[2], h3 = (float)h[3];
            s += h0 * h0 + h1 * h1 + h2 * h2 + h3 * h3;
        }
        #pragma unroll
        for (int off = 32; off > 0; off >>= 1) s += __shfl_down(s, off);
        if (lane == 0) nrm[r0 + lr] = s;
    }
    __syncthreads();

    // phase 2: panel-major writeout, 512B contiguous per wave-instruction
    const int rr = (lane >> 3) & 7;                 // row within segment
    const int gr = lane & 7;                        // 8B granule within row
    #pragma unroll
    for (int g = 0; g < 8; g++) {
        const int p = g * 4 + wave;                 // panel 0..31
        *(f16x4*)(dstp + (size_t)p * PSTRIDE + (size_t)(r0 + rr) * BK + gr * 4)
            = *(const f16x4*)&sh[rr][p * 32 + gr * 4];
    }
}

// ---------------------------------------------------------------- main GEMM
__global__ __launch_bounds__(256) void mmd_mfma(
    const f16_t* __restrict__ Xp, const f16_t* __restrict__ Yp,
    const float* __restrict__ nx, const float* __restrict__ ny,
    double* __restrict__ partials) {
    // Split A/B tiles, each BM x BK fp16 = 8 KB. Row r of a tile stores
    // logical chunk c (16 B) at phys chunk c ^ ((r>>1)&3) -- measured 0
    // bank conflicts (R7).
    __shared__ __align__(16) f16_t ldsA[TILE];
    __shared__ __align__(16) f16_t ldsB[TILE];
    __shared__ double wred[4];

    const int b = blockIdx.x;
    const f16_t *Ap, *Bp;             // packed panel bases (panel 0)
    const float *nA, *nB;
    int tr, tc;
    double coef;
    if (b < 2 * TRI) {
        int u = (b < TRI) ? b : b - TRI;
        int r = 0;
        while (u >= NT - r) { u -= NT - r; r++; }
        tr = r; tc = r + u;
        double w = (tr == tc) ? 1.0 : 2.0;   // off-diagonal tiles count twice
        if (b < TRI) { Ap = Xp; Bp = Xp; nA = nx; nB = nx;
                       coef = w / ((double)NROWS * (double)(NROWS - 1)); }
        else         { Ap = Yp; Bp = Yp; nA = ny; nB = ny;
                       coef = w / ((double)MROWS * (double)(MROWS - 1)); }
    } else {
        int u = b - 2 * TRI;
        tr = u >> 5; tc = u & 31;
        Ap = Xp; Bp = Yp; nA = nx; nB = ny;
        coef = -2.0 / ((double)NROWS * (double)MROWS);
    }

    const int t    = threadIdx.x;
    const int wave = t >> 6;            // 0..3; waves 2x2: wm=wave>>1, wn=wave&1
    const int lane = t & 63;
    const int wm   = wave >> 1;
    const int wn   = wave & 1;

    // staging: 16 glds instrs (2 tiles x 8 row-groups of 16 rows); wave w
    // issues instrs w*4 .. w*4+3. Per instr: 16 rows x 64B = CONTIGUOUS 1KB
    // in the packed panel. glds writes linearly: lane l -> row lr=l>>2,
    // phys chunk l&3; lane fetches global chunk (l&3)^((l>>3)&3) so phys
    // chunk p of row r holds logical p^((r>>1)&3).
    const int lr = lane >> 2;           // 0..15 within row-group
    const int lc = (lane & 3) ^ ((lane >> 3) & 3);
    const f16_t* gsrc[4];
    f16_t* ldst[4];
    #pragma unroll
    for (int i = 0; i < 4; i++) {
        int idx = wave * 4 + i;         // 0..15
        int tile = idx >> 3;            // 0=A, 1=B
        int rg   = idx & 7;             // row-group
        const f16_t* base = tile ? (Bp + (size_t)tc * BM * BK)
                                 : (Ap + (size_t)tr * BM * BK);
        gsrc[i] = base + (size_t)(rg * 16 + lr) * BK + lc * 8;
        ldst[i] = (tile ? ldsB : ldsA) + rg * 16 * BK;   // wave-uniform base
    }

    const int m    = lane & 15;         // row within 16x16 subtile
    const int quad = lane >> 4;         // k-chunk: k = quad*8 + j
    // read-side swizzled chunk offset: phys = quad ^ ((row>>1)&3); rows are
    // s*16 + m so f depends only on m.
    const int sw8  = (quad ^ ((m >> 1) & 3)) * 8;

    // hoist epilogue norm loads off the critical tail
    float na[16], nb[4];
    #pragma unroll
    for (int i = 0; i < 4; i++) {
        #pragma unroll
        for (int r = 0; r < 4; r++)
            na[i * 4 + r] = nA[tr * BM + wm * 64 + i * 16 + quad * 4 + r];
        nb[i] = nB[tc * BM + wn * 64 + i * 16 + m];
    }

    floatx4 acc_r[4][4];
    #pragma unroll
    for (int i = 0; i < 4; i++)
        #pragma unroll
        for (int j = 0; j < 4; j++) acc_r[i][j] = (floatx4){0.f, 0.f, 0.f, 0.f};

    for (int kt = 0; kt < NKT; kt++) {
        const size_t ko = (size_t)kt * PSTRIDE;   // next packed K-panel
        __syncthreads();                 // previous compute done before overwrite
        #pragma unroll
        for (int i = 0; i < 4; i++) {
            __builtin_amdgcn_global_load_lds(
                (const __attribute__((address_space(1))) void*)(gsrc[i] + ko),
                (__attribute__((address_space(3))) void*)ldst[i],
                16, 0, 0);
        }
        __syncthreads();                 // drains vmcnt before barrier

        f16x8 ah[4], bh[4];
        #pragma unroll
        for (int s = 0; s < 4; s++) {
            ah[s] = *(const f16x8*)&ldsA[(wm * 64 + s * 16 + m) * BK + sw8];
            bh[s] = *(const f16x8*)&ldsB[(wn * 64 + s * 16 + m) * BK + sw8];
        }
        #pragma unroll
        for (int i = 0; i < 4; i++)
            #pragma unroll
            for (int j = 0; j < 4; j++)
                acc_r[i][j] = __builtin_amdgcn_mfma_f32_16x16x32_f16(ah[i], bh[j], acc_r[i][j], 0, 0, 0);
    }

    // epilogue: C/D layout col=lane&15 (B-row), row=quad*4+reg (A-row)
    const float inv_s2 = 1.0f / 2025.0f;
    float lsum = 0.f;
    #pragma unroll
    for (int i = 0; i < 4; i++)
        #pragma unroll
        for (int j = 0; j < 4; j++)
            #pragma unroll
            for (int r = 0; r < 4; r++) {
                float arg = (2.f * acc_r[i][j][r] - na[i * 4 + r] - nb[j]) * inv_s2;
                lsum += __expf(arg);
            }

    // in-wave fp64 reduce (no barriers), then 4-wave LDS combine; plain store
    double d = (double)lsum;
    #pragma unroll
    for (int off = 32; off > 0; off >>= 1) d += __shfl_down(d, off);
    if (lane == 0) wred[wave] = d;
    __syncthreads();
    if (t == 0)
        partials[b] = (wred[0] + wred[1] + wred[2] + wred[3]) * coef;
}

__global__ __launch_bounds__(256) void final_reduce(const double* __restrict__ partials,
                                                    float* __restrict__ out) {
    __shared__ double red[256];
    int t = threadIdx.x;
    double s = 0.0;
    for (int i = t; i < NBLK; i += 256) s += partials[i];
    red[t] = s;
    __syncthreads();
    for (int off = 128; off > 0; off >>= 1) {
        if (t < off) red[t] += red[t + off];
        __syncthreads();
    }
    if (t == 0) {
        // analytic diagonal subtraction: 1/(n-1) + 1/(m-1)
        double mmd = red[0] - 1.0 / (double)(NROWS - 1) - 1.0 / (double)(MROWS - 1);
        out[0] = (float)mmd;
    }
}

extern "C" void kernel_launch(void* const* d_in, const int* in_sizes, int n_in,
                              void* d_out, int out_size, void* d_ws, size_t ws_size,
                              hipStream_t stream) {
    const float* X = (const float*)d_in[0];   // inputs  [4096,1024] fp32
    const float* Y = (const float*)d_in[1];   // samples [4096,1024] fp32
    float* out = (float*)d_out;

    // workspace: partials | nx | ny | Xp | Yp  (~16.7 MB)
    char* p = (char*)d_ws;
    double* partials = (double*)p;            p += ((size_t)NBLK * sizeof(double) + 255) & ~255ULL;
    float* nx = (float*)p;                    p += (size_t)NROWS * sizeof(float);
    float* ny = (float*)p;                    p += (size_t)MROWS * sizeof(float);
    f16_t* Xp = (f16_t*)p;                    p += (size_t)NROWS * DDIM * sizeof(f16_t);
    f16_t* Yp = (f16_t*)p;

    convert_kernel<<<1024, 256, 0, stream>>>(X, Y, Xp, Yp, nx, ny);
    mmd_mfma<<<NBLK, 256, 0, stream>>>(Xp, Yp, nx, ny, partials);
    final_reduce<<<1, 256, 0, stream>>>(partials, out);
}